// Round 13
// baseline (254.883 us; speedup 1.0000x reference)
//
#include <hip/hip_runtime.h>
#include <cstdint>
#include <cstddef>

typedef unsigned short u16;
typedef __attribute__((ext_vector_type(8))) short bf16x8;   // 8 bf16 (4 VGPR) MFMA frag
typedef __attribute__((ext_vector_type(8))) u16   u16x8;
typedef __attribute__((ext_vector_type(4))) short short4v;
typedef __attribute__((ext_vector_type(4))) float f32x4;
typedef __attribute__((ext_vector_type(16))) float f32x16;
typedef __attribute__((ext_vector_type(4))) unsigned int u32x4;

#define DEVI static __device__ __forceinline__

constexpr int B_   = 2;
constexpr int S_   = 2048;
constexpr int HID_ = 2048;
constexpr int NH_  = 16;
constexpr int NKV_ = 4;
constexpr int HD_  = 128;
constexpr int TOK  = B_ * S_;              // 4096
constexpr int OQKV = (NH_ + 2*NKV_) * HD_; // 3072

DEVI u16 f2bf(float f) {                  // RNE f32->bf16 (finite inputs)
  uint32_t u = __builtin_bit_cast(uint32_t, f);
  return (u16)((u + 0x7fffu + ((u >> 16) & 1u)) >> 16);
}
DEVI float bf2f(u16 h) { return __builtin_bit_cast(float, (uint32_t)h << 16); }

DEVI void gll16(const void* g, void* l) { // 16B global -> LDS direct
  __builtin_amdgcn_global_load_lds(
      (const __attribute__((address_space(1))) uint32_t*)g,
      (__attribute__((address_space(3))) uint32_t*)l, 16, 0, 0);
}

// ---------------- f32 -> bf16 convert, 3 buffers in one launch ------------
__global__ __launch_bounds__(256) void cvt3_kernel(
    const float* __restrict__ i0, u16* __restrict__ o0, int n0,
    const float* __restrict__ i1, u16* __restrict__ o1, int n1,
    const float* __restrict__ i2, u16* __restrict__ o2, int n2) {
  int idx = blockIdx.x * 256 + threadIdx.x;
  int stride = gridDim.x * 256;
#pragma unroll 1
  for (int pass = 0; pass < 3; ++pass) {
    const float* in = pass == 0 ? i0 : pass == 1 ? i1 : i2;
    u16* out       = pass == 0 ? o0 : pass == 1 ? o1 : o2;
    int n8         = pass == 0 ? n0 : pass == 1 ? n1 : n2;
    for (int i = idx; i < n8; i += stride) {
      const float4* p = reinterpret_cast<const float4*>(in) + (size_t)i * 2;
      float4 a = p[0], b = p[1];
      u16x8 v;
      v[0] = f2bf(a.x); v[1] = f2bf(a.y); v[2] = f2bf(a.z); v[3] = f2bf(a.w);
      v[4] = f2bf(b.x); v[5] = f2bf(b.y); v[6] = f2bf(b.z); v[7] = f2bf(b.w);
      reinterpret_cast<u16x8*>(out)[i] = v;
    }
  }
}

// ---------------- GEMM v2: C[m,n] = sum_k A[m,k]*B[n,k], bf16, 32x32 MFMA -
// BM=256 BN=128 BK=64, 512 threads = 8 waves (4M x 2N, 64x64 per wave).
// TRIPLE-buffered LDS (144KB) + depth-2 staging + COUNTED vmcnt(6): the
// m97-structure's vmcnt(0)-drain at each barrier is eliminated — stage(t+2)
// issues at tile t start; at tile end vmcnt(6) guarantees stage(t+1) landed
// while stage(t+2)'s 6 loads stay in flight across the raw s_barrier.
// T2 chunk-XOR swizzle (c ^= row&7) on stage-source + ds_read (same
// involution, linear gll16 dest per rule-21): conflict-free b128 reads.
template <bool OUT_BF16>
__global__ __launch_bounds__(512, 1) void gemm_bt2_kernel(
    const u16* __restrict__ A, const u16* __restrict__ B, void* __restrict__ Cv,
    int M, int N, int K) {
  constexpr int BM = 256, BN = 128, BK = 64;
  __shared__ __align__(16) u16 As[3][BM * BK];  // 3 x 32KB
  __shared__ __align__(16) u16 Bs[3][BN * BK];  // 3 x 16KB
  const int tid  = threadIdx.x;
  const int lane = tid & 63, wid = tid >> 6;
  const int hi   = lane >> 5;
  const int bm = blockIdx.x * BM;
  const int bn = blockIdx.y * BN;
  const int wm = (wid >> 1) * 64;   // 4 M-waves
  const int wn = (wid & 1) * 64;    // 2 N-waves

  f32x16 acc[2][2];
#pragma unroll
  for (int mf = 0; mf < 2; mf++)
#pragma unroll
    for (int nf = 0; nf < 2; nf++)
#pragma unroll
      for (int r = 0; r < 16; r++) acc[mf][nf][r] = 0.f;

  auto stage = [&](int t) {  // 6 gll16/thread; LDS linear, src pre-swizzled
    int buf = t % 3;
    const int k0 = t * BK;
#pragma unroll
    for (int i = 0; i < 4; i++) {          // A: 256x64 = 2048 chunks
      int e = i * 512 + tid;
      int row = e >> 3, c = e & 7;
      int cs = c ^ (row & 7);
      gll16(A + (size_t)(bm + row) * K + (k0 + cs * 8), &As[buf][e * 8]);
    }
#pragma unroll
    for (int i = 0; i < 2; i++) {          // B: 128x64 = 1024 chunks
      int e = i * 512 + tid;
      int row = e >> 3, c = e & 7;
      int cs = c ^ (row & 7);
      gll16(B + (size_t)(bn + row) * K + (k0 + cs * 8), &Bs[buf][e * 8]);
    }
  };

  const int nt = K / BK;  // 32
  stage(0);
  stage(1);
  asm volatile("s_waitcnt vmcnt(6)" ::: "memory");  // stage(0) landed
  __builtin_amdgcn_s_barrier();

  const int r7 = lane & 7;
  for (int t = 0; t < nt; ++t) {
    const int cur = t % 3;
    if (t + 2 < nt) stage(t + 2);  // issue-early; lands by end of tile t+1
    const u16* ab = &As[cur][(size_t)(wm + (lane & 31)) * BK];
    const u16* bb = &Bs[cur][(size_t)(wn + (lane & 31)) * BK];
#pragma unroll
    for (int k16 = 0; k16 < 4; k16++) {
      const int kc = k16 * 2 + hi;
      bf16x8 af[2], bfr[2];
#pragma unroll
      for (int mf = 0; mf < 2; mf++)
        af[mf] = *reinterpret_cast<const bf16x8*>(ab + mf * 32 * BK + ((kc ^ r7) << 3));
#pragma unroll
      for (int nf = 0; nf < 2; nf++)
        bfr[nf] = *reinterpret_cast<const bf16x8*>(bb + nf * 32 * BK + ((kc ^ r7) << 3));
      __builtin_amdgcn_s_setprio(1);
#pragma unroll
      for (int mf = 0; mf < 2; mf++)
#pragma unroll
        for (int nf = 0; nf < 2; nf++)
          acc[mf][nf] = __builtin_amdgcn_mfma_f32_32x32x16_bf16(af[mf], bfr[nf], acc[mf][nf], 0, 0, 0);
      __builtin_amdgcn_s_setprio(0);
    }
    if (t + 2 < nt)
      asm volatile("s_waitcnt vmcnt(6)" ::: "memory");   // stage(t+1) landed
    else if (t + 1 < nt)
      asm volatile("s_waitcnt vmcnt(0)" ::: "memory");   // last prefetch landed
    __builtin_amdgcn_s_barrier();
  }

  // C write: 32x32 C/D layout (m74/m101-verified): col=lane&31,
  // row = (r&3) + 8*(r>>2) + 4*hi
#pragma unroll
  for (int mf = 0; mf < 2; mf++)
#pragma unroll
    for (int nf = 0; nf < 2; nf++)
#pragma unroll
      for (int r = 0; r < 16; r++) {
        size_t row = bm + wm + mf * 32 + (r & 3) + 8 * (r >> 2) + 4 * hi;
        size_t col = bn + wn + nf * 32 + (lane & 31);
        if constexpr (OUT_BF16)
          reinterpret_cast<u16*>(Cv)[row * N + col] = f2bf(acc[mf][nf][r]);
        else
          reinterpret_cast<float*>(Cv)[row * N + col] = acc[mf][nf][r];
      }
}

// ---------------- fused RMSNorm + RoPE; one wave per (token, head-slot) ----
// Q rows are additionally scaled by 1/sqrt(128)*log2(e) so attention's
// softmax is a bare exp2.
__global__ __launch_bounds__(256) void rmsrope_kernel(
    const u16* __restrict__ qkv, const float* __restrict__ cosb,
    const float* __restrict__ sinb, const float* __restrict__ qw,
    const float* __restrict__ kw, u16* __restrict__ Q, u16* __restrict__ K) {
  int gw   = blockIdx.x * 4 + (threadIdx.x >> 6);
  int lane = threadIdx.x & 63;
  int tok  = gw / 20;
  int slot = gw - tok * 20;
  if (tok >= TOK) return;
  int b = tok >> 11, s = tok & (S_ - 1);
  const u16* src = qkv + (size_t)tok * OQKV + slot * HD_;
  float x0 = bf2f(src[lane]);
  float x1 = bf2f(src[lane + 64]);
  float ss = x0 * x0 + x1 * x1;
#pragma unroll
  for (int m = 1; m < 64; m <<= 1) ss += __shfl_xor(ss, m, 64);
  float r = rsqrtf(ss * (1.0f / 128.0f) + 1e-6f);
  const float* w = (slot < 16) ? qw : kw;
  x0 *= r * w[lane];
  x1 *= r * w[lane + 64];
  float c  = cosb[(size_t)tok * 64 + lane];
  float sn = sinb[(size_t)tok * 64 + lane];
  float partner = __shfl_xor(x0, 32, 64);
  float rot = (lane < 32) ? -partner : partner;
  x0 = x0 * c + rot * sn;
  const float QSC = 0.12751743f;  // (1/sqrt(128)) * log2(e)
  u16* dst;
  if (slot < 16) {
    x0 *= QSC; x1 *= QSC;
    dst = Q + (((size_t)b * NH_ + slot) * S_ + s) * HD_;
  } else {
    dst = K + (((size_t)b * NKV_ + (slot - 16)) * S_ + s) * HD_;
  }
  dst[lane]      = f2bf(x0);
  dst[lane + 64] = f2bf(x1);
}

// ---------------- flash attention v9: v7 staging + XCD-grouped blocks -----
// (unchanged from round 12: 104us, FETCH 12.4MB)
__global__ __launch_bounds__(512, 2) void attn_kernel(
    const u16* __restrict__ Q, const u16* __restrict__ K,
    const u16* __restrict__ QKVb, u16* __restrict__ O) {
  __shared__ __align__(16) u16 Ks[2][64 * 128];
  __shared__ __align__(16) u16 Vt[2][128 * 64];
  __shared__ float rs_lds[8][32];
  const int tid  = threadIdx.x;
  const int lane = tid & 63, wid = tid >> 6;
  const int q32 = lane & 31, hi = lane >> 5;
  const int i_   = blockIdx.x;
  const int xcd  = i_ & 7, s_ = i_ >> 3;
  const int b = xcd >> 2, kvh = xcd & 3;
  const int h = kvh * 4 + (s_ & 3);
  const int qt = s_ >> 2;                         // 0..7

  const u16* Qrow  = Q + ((size_t)(b * NH_ + h) * S_ + qt * 256 + wid * 32 + q32) * HD_;
  const u16* Kbase = K + (size_t)(b * NKV_ + kvh) * S_ * HD_;
  const u16* Vbase = QKVb + (size_t)b * S_ * OQKV + (size_t)(NH_ + NKV_) * HD_ + (size_t)kvh * HD_;

  bf16x8 qf[8];
#pragma unroll
  for (int m = 0; m < 8; m++)
    qf[m] = *reinterpret_cast<const bf16x8*>(Qrow + m * 16 + hi * 8);

  f32x16 acc[4];
#pragma unroll
  for (int n = 0; n < 4; n++)
#pragma unroll
    for (int r = 0; r < 16; r++) acc[n][r] = 0.f;

  float rs = 0.f;

  auto stageK = [&](int buf, int kt) {
#pragma unroll
    for (int i = 0; i < 2; i++) {
      int e = i * 512 + tid;
      int krow = e >> 4, ci = e & 15;
      int cs = ci ^ (krow & 15);
      gll16(Kbase + ((size_t)kt * 64 + krow) * HD_ + cs * 8, &Ks[buf][e * 8]);
    }
  };
  u16x8 vreg[4];
  auto loadV = [&](int kt) {
    if (tid < 256) {
      int kvb = tid >> 4, db = tid & 15;
#pragma unroll
      for (int i = 0; i < 4; i++)
        vreg[i] = *reinterpret_cast<const u16x8*>(
            Vbase + ((size_t)kt * 64 + kvb * 4 + i) * OQKV + db * 8);
    }
  };
  auto writeV = [&](int buf) {
    if (tid < 256) {
      int kvb = tid >> 4, db = tid & 15;
#pragma unroll
      for (int j = 0; j < 8; j++) {
        int d = db * 8 + j;
        int sw = (d ^ (d >> 3)) & 7;
        int off = d * 128 + ((((kvb >> 1) ^ sw)) << 4) + ((kvb & 1) << 3);
        short4v wv = {(short)vreg[0][j], (short)vreg[1][j],
                      (short)vreg[2][j], (short)vreg[3][j]};
        *reinterpret_cast<short4v*>(reinterpret_cast<char*>(Vt[buf]) + off) = wv;
      }
    }
  };

  stageK(0, 0);
  loadV(0);
  writeV(0);
  __syncthreads();

  const int NT = S_ / 64;  // 32
  for (int kt = 0; kt < NT; ++kt) {
    const int cur = kt & 1;
    if (kt + 1 < NT) { stageK(cur ^ 1, kt + 1); loadV(kt + 1); }

    const u16* kbp = &Ks[cur][(size_t)q32 * 128];
    const int swz = lane & 15;
    unsigned int pa[4][4];
#pragma unroll
    for (int kb = 0; kb < 2; kb++) {
      f32x16 s;
#pragma unroll
      for (int r = 0; r < 16; r++) s[r] = 0.f;
      __builtin_amdgcn_s_setprio(1);
#pragma unroll
      for (int m = 0; m < 8; m++) {
        bf16x8 kf = *reinterpret_cast<const bf16x8*>(
            kbp + kb * 32 * 128 + ((((m * 2 + hi) ^ swz)) << 3));
        s = __builtin_amdgcn_mfma_f32_32x32x16_bf16(kf, qf[m], s, 0, 0, 0);
      }
      __builtin_amdgcn_s_setprio(0);
      float p[16];
#pragma unroll
      for (int r = 0; r < 16; r++) {
        p[r] = exp2f(s[r]);
        rs += p[r];
      }
      unsigned int w[8];
#pragma unroll
      for (int m2 = 0; m2 < 8; m2++) {
        unsigned int wv;
        asm("v_cvt_pk_bf16_f32 %0, %1, %2" : "=v"(wv) : "v"(p[2 * m2]), "v"(p[2 * m2 + 1]));
        w[m2] = wv;
      }
#pragma unroll
      for (int tp = 0; tp < 2; tp++) {
        unsigned int a0 = w[4 * tp + 0], b0 = w[4 * tp + 2];
        unsigned int a1 = w[4 * tp + 1], b1 = w[4 * tp + 3];
        asm("v_permlane32_swap_b32 %0, %1" : "+v"(a0), "+v"(b0));
        asm("v_permlane32_swap_b32 %0, %1" : "+v"(a1), "+v"(b1));
        pa[kb * 2 + tp][0] = a0;
        pa[kb * 2 + tp][1] = a1;
        pa[kb * 2 + tp][2] = b0;
        pa[kb * 2 + tp][3] = b1;
      }
    }

#pragma unroll
    for (int t = 0; t < 4; t++) {
      union { u32x4 u; bf16x8 h; } pf;
      pf.u = (u32x4){pa[t][0], pa[t][1], pa[t][2], pa[t][3]};
      __builtin_amdgcn_s_setprio(1);
#pragma unroll
      for (int n = 0; n < 4; n++) {
        int d = n * 32 + q32;
        int sw = (d ^ (d >> 3)) & 7;
        bf16x8 vf = *reinterpret_cast<const bf16x8*>(
            reinterpret_cast<const char*>(Vt[cur]) + d * 128 + (((t * 2 + hi) ^ sw) << 4));
        acc[n] = __builtin_amdgcn_mfma_f32_32x32x16_bf16(pf.h, vf, acc[n], 0, 0, 0);
      }
      __builtin_amdgcn_s_setprio(0);
    }

    if (kt + 1 < NT) writeV(cur ^ 1);
    __syncthreads();
  }

  float rtot = rs + __shfl_xor(rs, 32, 64);
  if (lane < 32) rs_lds[wid][q32] = rtot;
  __syncthreads();
  float rinv[16];
#pragma unroll
  for (int r = 0; r < 16; r++)
    rinv[r] = 1.0f / rs_lds[wid][(r & 3) + 8 * (r >> 2) + 4 * hi];

  const int qrow0 = qt * 256 + wid * 32;
  u16* ob = O + ((size_t)b * S_ + qrow0) * HID_ + h * HD_ + q32;
#pragma unroll
  for (int n = 0; n < 4; n++)
#pragma unroll
    for (int r = 0; r < 16; r++) {
      int qr = (r & 3) + 8 * (r >> 2) + 4 * hi;
      ob[(size_t)qr * HID_ + n * 32] = f2bf(acc[n][r] * rinv[r]);
    }
}

// ---------------------------------------------------------------------------
extern "C" void kernel_launch(void* const* d_in, const int* in_sizes, int n_in,
                              void* d_out, int out_size, void* d_ws, size_t ws_size,
                              hipStream_t stream) {
  (void)in_sizes; (void)n_in; (void)out_size; (void)ws_size;
  const float* hs   = (const float*)d_in[0];
  const float* cosb = (const float*)d_in[1];
  const float* sinb = (const float*)d_in[2];
  const float* wqkv = (const float*)d_in[3];
  const float* qw   = (const float*)d_in[4];
  const float* kw   = (const float*)d_in[5];
  const float* wd   = (const float*)d_in[6];
  float* out = (float*)d_out;
  char* ws = (char*)d_ws;
  constexpr size_t MB = 1048576;
  u16* Xb    = (u16*)(ws + 0 * MB);    // 16 MB  X bf16        [4096][2048]
  u16* Wqkvb = (u16*)(ws + 16 * MB);   // 12 MB  w_qkv bf16    [3072][2048]
  u16* Wdb   = (u16*)(ws + 28 * MB);   //  8 MB  w_dense bf16  [2048][2048]
  u16* QKVb  = (u16*)(ws + 36 * MB);   // 24 MB  qkv bf16      [4096][3072]
  u16* Qb    = (u16*)(ws + 60 * MB);   // 16 MB  Q             [B][NH][S][HD]
  u16* Kb    = (u16*)(ws + 76 * MB);   //  4 MB  K             [B][NKV][S][HD]
  u16* Ob    = (u16*)(ws + 80 * MB);   // 16 MB  attn out      [B][S][NH*HD]

  cvt3_kernel<<<2048, 256, 0, stream>>>(hs, Xb, TOK * HID_ / 8,
                                        wqkv, Wqkvb, OQKV * HID_ / 8,
                                        wd, Wdb, HID_ * HID_ / 8);

  gemm_bt2_kernel<true><<<dim3(TOK / 256, OQKV / 128), 512, 0, stream>>>(
      Xb, Wqkvb, QKVb, TOK, OQKV, HID_);

  rmsrope_kernel<<<TOK * 20 / 4, 256, 0, stream>>>(QKVb, cosb, sinb, qw, kw, Qb, Kb);

  attn_kernel<<<256, 512, 0, stream>>>(Qb, Kb, QKVb, Ob);

  gemm_bt2_kernel<false><<<dim3(TOK / 256, HID_ / 128), 512, 0, stream>>>(
      Ob, Wdb, out, TOK, HID_, HID_);
}

// Round 14
// 252.458 us; speedup vs baseline: 1.0096x; 1.0096x over previous
//
#include <hip/hip_runtime.h>
#include <cstdint>
#include <cstddef>

typedef unsigned short u16;
typedef __attribute__((ext_vector_type(8))) short bf16x8;   // 8 bf16 (4 VGPR) MFMA frag
typedef __attribute__((ext_vector_type(8))) u16   u16x8;
typedef __attribute__((ext_vector_type(4))) short short4v;
typedef __attribute__((ext_vector_type(4))) float f32x4;
typedef __attribute__((ext_vector_type(16))) float f32x16;
typedef __attribute__((ext_vector_type(4))) unsigned int u32x4;

#define DEVI static __device__ __forceinline__

constexpr int B_   = 2;
constexpr int S_   = 2048;
constexpr int HID_ = 2048;
constexpr int NH_  = 16;
constexpr int NKV_ = 4;
constexpr int HD_  = 128;
constexpr int TOK  = B_ * S_;              // 4096
constexpr int OQKV = (NH_ + 2*NKV_) * HD_; // 3072

DEVI u16 f2bf(float f) {                  // RNE f32->bf16 (finite inputs)
  uint32_t u = __builtin_bit_cast(uint32_t, f);
  return (u16)((u + 0x7fffu + ((u >> 16) & 1u)) >> 16);
}
DEVI float bf2f(u16 h) { return __builtin_bit_cast(float, (uint32_t)h << 16); }

DEVI void gll16(const void* g, void* l) { // 16B global -> LDS direct
  __builtin_amdgcn_global_load_lds(
      (const __attribute__((address_space(1))) uint32_t*)g,
      (__attribute__((address_space(3))) uint32_t*)l, 16, 0, 0);
}

// ---------------- f32 -> bf16 convert, 3 buffers in one launch ------------
__global__ __launch_bounds__(256) void cvt3_kernel(
    const float* __restrict__ i0, u16* __restrict__ o0, int n0,
    const float* __restrict__ i1, u16* __restrict__ o1, int n1,
    const float* __restrict__ i2, u16* __restrict__ o2, int n2) {
  int idx = blockIdx.x * 256 + threadIdx.x;
  int stride = gridDim.x * 256;
#pragma unroll 1
  for (int pass = 0; pass < 3; ++pass) {
    const float* in = pass == 0 ? i0 : pass == 1 ? i1 : i2;
    u16* out       = pass == 0 ? o0 : pass == 1 ? o1 : o2;
    int n8         = pass == 0 ? n0 : pass == 1 ? n1 : n2;
    for (int i = idx; i < n8; i += stride) {
      const float4* p = reinterpret_cast<const float4*>(in) + (size_t)i * 2;
      float4 a = p[0], b = p[1];
      u16x8 v;
      v[0] = f2bf(a.x); v[1] = f2bf(a.y); v[2] = f2bf(a.z); v[3] = f2bf(a.w);
      v[4] = f2bf(b.x); v[5] = f2bf(b.y); v[6] = f2bf(b.z); v[7] = f2bf(b.w);
      reinterpret_cast<u16x8*>(out)[i] = v;
    }
  }
}

// ---------------- C[m,n] = sum_k A[m,k] * B[n,k]  (both row-major, bf16) ---
// Round-12-verified 128x128 structure (BK=32, 4 waves, global_load_lds,
// double-buffer; ~900 TF via 4 blocks/CU TLP).
template <bool OUT_BF16>
__global__ __launch_bounds__(256) void gemm_bt_kernel(
    const u16* __restrict__ A, const u16* __restrict__ B, void* __restrict__ Cv,
    int M, int N, int K) {
  constexpr int BM = 128, BN = 128, BK = 32;
  __shared__ __align__(16) u16 As[2][BM * BK];
  __shared__ __align__(16) u16 Bs[2][BN * BK];
  const int tid  = threadIdx.x;
  const int lane = tid & 63;
  const int wid  = tid >> 6;
  const int bm = blockIdx.x * BM;
  const int bn = blockIdx.y * BN;
  const int wm = (wid >> 1) * 64;
  const int wn = (wid & 1) * 64;
  const int fr = lane & 15, fg = lane >> 4;

  const f32x4 fzero = {0.f, 0.f, 0.f, 0.f};
  f32x4 acc[4][4];
#pragma unroll
  for (int m = 0; m < 4; m++)
#pragma unroll
    for (int n = 0; n < 4; n++) acc[m][n] = fzero;

  auto stage = [&](int buf, int k0) {
#pragma unroll
    for (int i = 0; i < 2; i++) {
      int e = i * 256 + tid;  // 8-elem group: row e>>2, col (e&3)*8
      gll16(A + (size_t)(bm + (e >> 2)) * K + (k0 + (e & 3) * 8), &As[buf][e * 8]);
    }
#pragma unroll
    for (int i = 0; i < 2; i++) {
      int e = i * 256 + tid;
      gll16(B + (size_t)(bn + (e >> 2)) * K + (k0 + (e & 3) * 8), &Bs[buf][e * 8]);
    }
  };

  stage(0, 0);
  __syncthreads();
  const int nt = K / BK;
  for (int t = 0; t < nt; ++t) {
    int cur = t & 1;
    if (t + 1 < nt) stage(cur ^ 1, (t + 1) * BK);
    bf16x8 af[4], bfv[4];
#pragma unroll
    for (int m = 0; m < 4; m++)
      af[m] = *reinterpret_cast<const bf16x8*>(&As[cur][(wm + m * 16 + fr) * BK + fg * 8]);
#pragma unroll
    for (int n = 0; n < 4; n++)
      bfv[n] = *reinterpret_cast<const bf16x8*>(&Bs[cur][(wn + n * 16 + fr) * BK + fg * 8]);
#pragma unroll
    for (int m = 0; m < 4; m++)
#pragma unroll
      for (int n = 0; n < 4; n++)
        acc[m][n] = __builtin_amdgcn_mfma_f32_16x16x32_bf16(af[m], bfv[n], acc[m][n], 0, 0, 0);
    __syncthreads();
  }

#pragma unroll
  for (int m = 0; m < 4; m++)
#pragma unroll
    for (int n = 0; n < 4; n++)
#pragma unroll
      for (int j = 0; j < 4; j++) {
        size_t row = bm + wm + m * 16 + fg * 4 + j;
        size_t col = bn + wn + n * 16 + fr;
        if constexpr (OUT_BF16)
          reinterpret_cast<u16*>(Cv)[row * N + col] = f2bf(acc[m][n][j]);
        else
          reinterpret_cast<float*>(Cv)[row * N + col] = acc[m][n][j];
      }
}

// ---------------- QKV GEMM with FUSED RMSNorm + RoPE epilogue -------------
// Same verified GEMM body; BN=128=HD so blockIdx.y = head-slot and each
// block owns one full head-slot x 128 tokens. In the 16x16 C-layout a lane
// holds cols {fr,16+fr,32+fr,48+fr} of its wn-half -> RoPE pair (d,d+32)
// is LANE-LOCAL (n=0<->2, n=1<->3; only wn==0 waves rope). RMS row-sum:
// 16-lane shfl_xor + cross-wave (wid^1) LDS add. Q slots (<16) -> Qo with
// QSC=log2e/sqrt(128) folded; K slots (16..19) -> Ko; V slots (>=20) ->
// plain bf16 write to QKVb (attn reads V there). Q/K skip the QKVb write.
__global__ __launch_bounds__(256) void gemm_qkv_kernel(
    const u16* __restrict__ A, const u16* __restrict__ B,
    u16* __restrict__ QKVb, u16* __restrict__ Qo, u16* __restrict__ Ko,
    const float* __restrict__ cosb, const float* __restrict__ sinb,
    const float* __restrict__ qw, const float* __restrict__ kw) {
  constexpr int N = OQKV, K = HID_;
  constexpr int BM = 128, BN = 128, BK = 32;
  __shared__ __align__(16) u16 As[2][BM * BK];
  __shared__ __align__(16) u16 Bs[2][BN * BK];
  __shared__ float rsum[4][64];
  const int tid  = threadIdx.x;
  const int lane = tid & 63;
  const int wid  = tid >> 6;
  const int bm = blockIdx.x * BM;
  const int bn = blockIdx.y * BN;
  const int wm = (wid >> 1) * 64;
  const int wn = (wid & 1) * 64;
  const int fr = lane & 15, fg = lane >> 4;

  const f32x4 fzero = {0.f, 0.f, 0.f, 0.f};
  f32x4 acc[4][4];
#pragma unroll
  for (int m = 0; m < 4; m++)
#pragma unroll
    for (int n = 0; n < 4; n++) acc[m][n] = fzero;

  auto stage = [&](int buf, int k0) {
#pragma unroll
    for (int i = 0; i < 2; i++) {
      int e = i * 256 + tid;
      gll16(A + (size_t)(bm + (e >> 2)) * K + (k0 + (e & 3) * 8), &As[buf][e * 8]);
    }
#pragma unroll
    for (int i = 0; i < 2; i++) {
      int e = i * 256 + tid;
      gll16(B + (size_t)(bn + (e >> 2)) * K + (k0 + (e & 3) * 8), &Bs[buf][e * 8]);
    }
  };

  stage(0, 0);
  __syncthreads();
  const int nt = K / BK;
  for (int t = 0; t < nt; ++t) {
    int cur = t & 1;
    if (t + 1 < nt) stage(cur ^ 1, (t + 1) * BK);
    bf16x8 af[4], bfv[4];
#pragma unroll
    for (int m = 0; m < 4; m++)
      af[m] = *reinterpret_cast<const bf16x8*>(&As[cur][(wm + m * 16 + fr) * BK + fg * 8]);
#pragma unroll
    for (int n = 0; n < 4; n++)
      bfv[n] = *reinterpret_cast<const bf16x8*>(&Bs[cur][(wn + n * 16 + fr) * BK + fg * 8]);
#pragma unroll
    for (int m = 0; m < 4; m++)
#pragma unroll
      for (int n = 0; n < 4; n++)
        acc[m][n] = __builtin_amdgcn_mfma_f32_16x16x32_bf16(af[m], bfv[n], acc[m][n], 0, 0, 0);
    __syncthreads();
  }

  const int slot = blockIdx.y;  // BN == HD: one head-slot per block column
  if (slot >= 20) {             // V: plain bf16 write into QKVb
#pragma unroll
    for (int m = 0; m < 4; m++)
#pragma unroll
      for (int n = 0; n < 4; n++)
#pragma unroll
        for (int j = 0; j < 4; j++) {
          size_t row = bm + wm + m * 16 + fg * 4 + j;
          size_t col = bn + wn + n * 16 + fr;
          QKVb[row * N + col] = f2bf(acc[m][n][j]);
        }
    return;
  }

  // ---- RMSNorm: per-row sum of squares over 128 cols ----
  float ssq[16];
#pragma unroll
  for (int m = 0; m < 4; m++)
#pragma unroll
    for (int j = 0; j < 4; j++) {
      float s2 = 0.f;
#pragma unroll
      for (int n = 0; n < 4; n++) { float v = acc[m][n][j]; s2 = fmaf(v, v, s2); }
      ssq[m * 4 + j] = s2;
    }
#pragma unroll
  for (int msk = 1; msk < 16; msk <<= 1)
#pragma unroll
    for (int i = 0; i < 16; i++) ssq[i] += __shfl_xor(ssq[i], msk, 64);
  if (fr == 0) {
#pragma unroll
    for (int i = 0; i < 16; i++)
      rsum[wid][(i >> 2) * 16 + fg * 4 + (i & 3)] = ssq[i];
  }
  __syncthreads();

  const float* gam = (slot < 16) ? qw : kw;
  const float g0 = gam[wn + fr],      g1 = gam[wn + 16 + fr];
  const float g2 = gam[wn + 32 + fr], g3 = gam[wn + 48 + fr];
  const float qsc = (slot < 16) ? 0.12751743f : 1.0f;  // (1/sqrt(128))*log2e

#pragma unroll
  for (int m = 0; m < 4; m++)
#pragma unroll
    for (int j = 0; j < 4; j++) {
      const int i = m * 4 + j;
      float tot = ssq[i] + rsum[wid ^ 1][m * 16 + fg * 4 + j];
      float rv  = rsqrtf(tot * (1.0f / 128.0f) + 1e-6f);
      size_t tok = (size_t)(bm + wm + m * 16 + fg * 4 + j);
      float v0 = acc[m][0][j] * rv * g0, v1 = acc[m][1][j] * rv * g1;
      float v2 = acc[m][2][j] * rv * g2, v3 = acc[m][3][j] * rv * g3;
      if (wn == 0) {  // cols 0..63 = RoPE range; pairs are lane-local
        const float* cb = cosb + tok * 64;
        const float* sb = sinb + tok * 64;
        float c0 = cb[fr], c1 = cb[16 + fr], c2 = cb[32 + fr], c3 = cb[48 + fr];
        float n0 = sb[fr], n1 = sb[16 + fr], n2 = sb[32 + fr], n3 = sb[48 + fr];
        float t0 = v0 * c0 - v2 * n0;   // d<32:  x*cos - x[d+32]*sin
        float t1 = v1 * c1 - v3 * n1;
        float t2 = v2 * c2 + v0 * n2;   // d>=32: x*cos + x[d-32]*sin
        float t3 = v3 * c3 + v1 * n3;
        v0 = t0; v1 = t1; v2 = t2; v3 = t3;
      }
      v0 *= qsc; v1 *= qsc; v2 *= qsc; v3 *= qsc;
      int b = (int)(tok >> 11), s = (int)(tok & (S_ - 1));
      u16* dst = (slot < 16)
          ? Qo + (((size_t)b * NH_ + slot) * S_ + s) * HD_
          : Ko + (((size_t)b * NKV_ + (slot - 16)) * S_ + s) * HD_;
      dst[wn + fr]      = f2bf(v0);
      dst[wn + 16 + fr] = f2bf(v1);
      dst[wn + 32 + fr] = f2bf(v2);
      dst[wn + 48 + fr] = f2bf(v3);
    }
}

// ---------------- flash attention v9: v7 staging + XCD-grouped blocks -----
// (unchanged from round 12: 104us, FETCH 12.4MB)
__global__ __launch_bounds__(512, 2) void attn_kernel(
    const u16* __restrict__ Q, const u16* __restrict__ K,
    const u16* __restrict__ QKVb, u16* __restrict__ O) {
  __shared__ __align__(16) u16 Ks[2][64 * 128];
  __shared__ __align__(16) u16 Vt[2][128 * 64];
  __shared__ float rs_lds[8][32];
  const int tid  = threadIdx.x;
  const int lane = tid & 63, wid = tid >> 6;
  const int q32 = lane & 31, hi = lane >> 5;
  const int i_   = blockIdx.x;
  const int xcd  = i_ & 7, s_ = i_ >> 3;
  const int b = xcd >> 2, kvh = xcd & 3;
  const int h = kvh * 4 + (s_ & 3);
  const int qt = s_ >> 2;                         // 0..7

  const u16* Qrow  = Q + ((size_t)(b * NH_ + h) * S_ + qt * 256 + wid * 32 + q32) * HD_;
  const u16* Kbase = K + (size_t)(b * NKV_ + kvh) * S_ * HD_;
  const u16* Vbase = QKVb + (size_t)b * S_ * OQKV + (size_t)(NH_ + NKV_) * HD_ + (size_t)kvh * HD_;

  bf16x8 qf[8];
#pragma unroll
  for (int m = 0; m < 8; m++)
    qf[m] = *reinterpret_cast<const bf16x8*>(Qrow + m * 16 + hi * 8);

  f32x16 acc[4];
#pragma unroll
  for (int n = 0; n < 4; n++)
#pragma unroll
    for (int r = 0; r < 16; r++) acc[n][r] = 0.f;

  float rs = 0.f;

  auto stageK = [&](int buf, int kt) {
#pragma unroll
    for (int i = 0; i < 2; i++) {
      int e = i * 512 + tid;
      int krow = e >> 4, ci = e & 15;
      int cs = ci ^ (krow & 15);
      gll16(Kbase + ((size_t)kt * 64 + krow) * HD_ + cs * 8, &Ks[buf][e * 8]);
    }
  };
  u16x8 vreg[4];
  auto loadV = [&](int kt) {
    if (tid < 256) {
      int kvb = tid >> 4, db = tid & 15;
#pragma unroll
      for (int i = 0; i < 4; i++)
        vreg[i] = *reinterpret_cast<const u16x8*>(
            Vbase + ((size_t)kt * 64 + kvb * 4 + i) * OQKV + db * 8);
    }
  };
  auto writeV = [&](int buf) {
    if (tid < 256) {
      int kvb = tid >> 4, db = tid & 15;
#pragma unroll
      for (int j = 0; j < 8; j++) {
        int d = db * 8 + j;
        int sw = (d ^ (d >> 3)) & 7;
        int off = d * 128 + ((((kvb >> 1) ^ sw)) << 4) + ((kvb & 1) << 3);
        short4v wv = {(short)vreg[0][j], (short)vreg[1][j],
                      (short)vreg[2][j], (short)vreg[3][j]};
        *reinterpret_cast<short4v*>(reinterpret_cast<char*>(Vt[buf]) + off) = wv;
      }
    }
  };

  stageK(0, 0);
  loadV(0);
  writeV(0);
  __syncthreads();

  const int NT = S_ / 64;  // 32
  for (int kt = 0; kt < NT; ++kt) {
    const int cur = kt & 1;
    if (kt + 1 < NT) { stageK(cur ^ 1, kt + 1); loadV(kt + 1); }

    const u16* kbp = &Ks[cur][(size_t)q32 * 128];
    const int swz = lane & 15;
    unsigned int pa[4][4];
#pragma unroll
    for (int kb = 0; kb < 2; kb++) {
      f32x16 s;
#pragma unroll
      for (int r = 0; r < 16; r++) s[r] = 0.f;
      __builtin_amdgcn_s_setprio(1);
#pragma unroll
      for (int m = 0; m < 8; m++) {
        bf16x8 kf = *reinterpret_cast<const bf16x8*>(
            kbp + kb * 32 * 128 + ((((m * 2 + hi) ^ swz)) << 3));
        s = __builtin_amdgcn_mfma_f32_32x32x16_bf16(kf, qf[m], s, 0, 0, 0);
      }
      __builtin_amdgcn_s_setprio(0);
      float p[16];
#pragma unroll
      for (int r = 0; r < 16; r++) {
        p[r] = exp2f(s[r]);
        rs += p[r];
      }
      unsigned int w[8];
#pragma unroll
      for (int m2 = 0; m2 < 8; m2++) {
        unsigned int wv;
        asm("v_cvt_pk_bf16_f32 %0, %1, %2" : "=v"(wv) : "v"(p[2 * m2]), "v"(p[2 * m2 + 1]));
        w[m2] = wv;
      }
#pragma unroll
      for (int tp = 0; tp < 2; tp++) {
        unsigned int a0 = w[4 * tp + 0], b0 = w[4 * tp + 2];
        unsigned int a1 = w[4 * tp + 1], b1 = w[4 * tp + 3];
        asm("v_permlane32_swap_b32 %0, %1" : "+v"(a0), "+v"(b0));
        asm("v_permlane32_swap_b32 %0, %1" : "+v"(a1), "+v"(b1));
        pa[kb * 2 + tp][0] = a0;
        pa[kb * 2 + tp][1] = a1;
        pa[kb * 2 + tp][2] = b0;
        pa[kb * 2 + tp][3] = b1;
      }
    }

#pragma unroll
    for (int t = 0; t < 4; t++) {
      union { u32x4 u; bf16x8 h; } pf;
      pf.u = (u32x4){pa[t][0], pa[t][1], pa[t][2], pa[t][3]};
      __builtin_amdgcn_s_setprio(1);
#pragma unroll
      for (int n = 0; n < 4; n++) {
        int d = n * 32 + q32;
        int sw = (d ^ (d >> 3)) & 7;
        bf16x8 vf = *reinterpret_cast<const bf16x8*>(
            reinterpret_cast<const char*>(Vt[cur]) + d * 128 + (((t * 2 + hi) ^ sw) << 4));
        acc[n] = __builtin_amdgcn_mfma_f32_32x32x16_bf16(pf.h, vf, acc[n], 0, 0, 0);
      }
      __builtin_amdgcn_s_setprio(0);
    }

    if (kt + 1 < NT) writeV(cur ^ 1);
    __syncthreads();
  }

  float rtot = rs + __shfl_xor(rs, 32, 64);
  if (lane < 32) rs_lds[wid][q32] = rtot;
  __syncthreads();
  float rinv[16];
#pragma unroll
  for (int r = 0; r < 16; r++)
    rinv[r] = 1.0f / rs_lds[wid][(r & 3) + 8 * (r >> 2) + 4 * hi];

  const int qrow0 = qt * 256 + wid * 32;
  u16* ob = O + ((size_t)b * S_ + qrow0) * HID_ + h * HD_ + q32;
#pragma unroll
  for (int n = 0; n < 4; n++)
#pragma unroll
    for (int r = 0; r < 16; r++) {
      int qr = (r & 3) + 8 * (r >> 2) + 4 * hi;
      ob[(size_t)qr * HID_ + n * 32] = f2bf(acc[n][r] * rinv[r]);
    }
}

// ---------------------------------------------------------------------------
extern "C" void kernel_launch(void* const* d_in, const int* in_sizes, int n_in,
                              void* d_out, int out_size, void* d_ws, size_t ws_size,
                              hipStream_t stream) {
  (void)in_sizes; (void)n_in; (void)out_size; (void)ws_size;
  const float* hs   = (const float*)d_in[0];
  const float* cosb = (const float*)d_in[1];
  const float* sinb = (const float*)d_in[2];
  const float* wqkv = (const float*)d_in[3];
  const float* qw   = (const float*)d_in[4];
  const float* kw   = (const float*)d_in[5];
  const float* wd   = (const float*)d_in[6];
  float* out = (float*)d_out;
  char* ws = (char*)d_ws;
  constexpr size_t MB = 1048576;
  u16* Xb    = (u16*)(ws + 0 * MB);    // 16 MB  X bf16        [4096][2048]
  u16* Wqkvb = (u16*)(ws + 16 * MB);   // 12 MB  w_qkv bf16    [3072][2048]
  u16* Wdb   = (u16*)(ws + 28 * MB);   //  8 MB  w_dense bf16  [2048][2048]
  u16* QKVb  = (u16*)(ws + 36 * MB);   // 24 MB  qkv bf16      [4096][3072] (V slots live)
  u16* Qb    = (u16*)(ws + 60 * MB);   // 16 MB  Q             [B][NH][S][HD]
  u16* Kb    = (u16*)(ws + 76 * MB);   //  4 MB  K             [B][NKV][S][HD]
  u16* Ob    = (u16*)(ws + 80 * MB);   // 16 MB  attn out      [B][S][NH*HD]

  cvt3_kernel<<<2048, 256, 0, stream>>>(hs, Xb, TOK * HID_ / 8,
                                        wqkv, Wqkvb, OQKV * HID_ / 8,
                                        wd, Wdb, HID_ * HID_ / 8);

  gemm_qkv_kernel<<<dim3(TOK / 128, OQKV / 128), 256, 0, stream>>>(
      Xb, Wqkvb, QKVb, Qb, Kb, cosb, sinb, qw, kw);

  attn_kernel<<<256, 512, 0, stream>>>(Qb, Kb, QKVb, Ob);

  gemm_bt_kernel<false><<<dim3(TOK / 128, HID_ / 128), 256, 0, stream>>>(
      Ob, Wdb, out, TOK, HID_, HID_);
}

// Round 15
// 226.975 us; speedup vs baseline: 1.1230x; 1.1123x over previous
//
#include <hip/hip_runtime.h>
#include <cstdint>
#include <cstddef>

typedef unsigned short u16;
typedef __attribute__((ext_vector_type(8))) short bf16x8;   // 8 bf16 (4 VGPR) MFMA frag
typedef __attribute__((ext_vector_type(8))) u16   u16x8;
typedef __attribute__((ext_vector_type(4))) short short4v;
typedef __attribute__((ext_vector_type(4))) float f32x4;
typedef __attribute__((ext_vector_type(16))) float f32x16;
typedef __attribute__((ext_vector_type(4))) unsigned int u32x4;

#define DEVI static __device__ __forceinline__

constexpr int B_   = 2;
constexpr int S_   = 2048;
constexpr int HID_ = 2048;
constexpr int NH_  = 16;
constexpr int NKV_ = 4;
constexpr int HD_  = 128;
constexpr int TOK  = B_ * S_;              // 4096
constexpr int OQKV = (NH_ + 2*NKV_) * HD_; // 3072

DEVI u16 f2bf(float f) {                  // RNE f32->bf16 (finite inputs)
  uint32_t u = __builtin_bit_cast(uint32_t, f);
  return (u16)((u + 0x7fffu + ((u >> 16) & 1u)) >> 16);
}
DEVI float bf2f(u16 h) { return __builtin_bit_cast(float, (uint32_t)h << 16); }

DEVI void gll16(const void* g, void* l) { // 16B global -> LDS direct
  __builtin_amdgcn_global_load_lds(
      (const __attribute__((address_space(1))) uint32_t*)g,
      (__attribute__((address_space(3))) uint32_t*)l, 16, 0, 0);
}

// ---------------- f32 -> bf16 convert, 3 buffers in one launch ------------
__global__ __launch_bounds__(256) void cvt3_kernel(
    const float* __restrict__ i0, u16* __restrict__ o0, int n0,
    const float* __restrict__ i1, u16* __restrict__ o1, int n1,
    const float* __restrict__ i2, u16* __restrict__ o2, int n2) {
  int idx = blockIdx.x * 256 + threadIdx.x;
  int stride = gridDim.x * 256;
#pragma unroll 1
  for (int pass = 0; pass < 3; ++pass) {
    const float* in = pass == 0 ? i0 : pass == 1 ? i1 : i2;
    u16* out       = pass == 0 ? o0 : pass == 1 ? o1 : o2;
    int n8         = pass == 0 ? n0 : pass == 1 ? n1 : n2;
    for (int i = idx; i < n8; i += stride) {
      const float4* p = reinterpret_cast<const float4*>(in) + (size_t)i * 2;
      float4 a = p[0], b = p[1];
      u16x8 v;
      v[0] = f2bf(a.x); v[1] = f2bf(a.y); v[2] = f2bf(a.z); v[3] = f2bf(a.w);
      v[4] = f2bf(b.x); v[5] = f2bf(b.y); v[6] = f2bf(b.z); v[7] = f2bf(b.w);
      reinterpret_cast<u16x8*>(out)[i] = v;
    }
  }
}

// ---------------- C[m,n] = sum_k A[m,k] * B[n,k]  (both row-major, bf16) ---
// Round-12-verified 128x128 structure (BK=32, 4 waves, global_load_lds,
// double-buffer). NEW (T1): 1-D grid with XCD-chunked decode — hw maps
// blockIdx%8 -> XCD, so xcd = id&7 owns a contiguous slab of gy/8 B-panels,
// traversed y-fastest (each A-panel reused rpx times back-to-back; slab's
// B-panels ~1-1.5MB stay L2-resident; concurrent s across XCDs aligns
// A-panel fetches in time for L3 hits).
template <bool OUT_BF16>
__global__ __launch_bounds__(256) void gemm_bt_kernel(
    const u16* __restrict__ A, const u16* __restrict__ B, void* __restrict__ Cv,
    int M, int N, int K) {
  constexpr int BM = 128, BN = 128, BK = 32;
  __shared__ __align__(16) u16 As[2][BM * BK];
  __shared__ __align__(16) u16 Bs[2][BN * BK];
  const int tid  = threadIdx.x;
  const int lane = tid & 63;
  const int wid  = tid >> 6;
  // XCD-chunked decode (requires gy % 8 == 0; 24 and 16 both qualify)
  const int gy  = N >> 7;
  const int rpx = gy >> 3;                  // y-rows per XCD
  const int xcd = blockIdx.x & 7;
  const int s   = blockIdx.x >> 3;          // 0 .. gx*rpx-1
  const int bxi = s / rpx;
  const int byi = xcd * rpx + (s - bxi * rpx);
  const int bm = bxi * BM;
  const int bn = byi * BN;
  const int wm = (wid >> 1) * 64;
  const int wn = (wid & 1) * 64;
  const int fr = lane & 15, fg = lane >> 4;

  const f32x4 fzero = {0.f, 0.f, 0.f, 0.f};
  f32x4 acc[4][4];
#pragma unroll
  for (int m = 0; m < 4; m++)
#pragma unroll
    for (int n = 0; n < 4; n++) acc[m][n] = fzero;

  auto stage = [&](int buf, int k0) {
#pragma unroll
    for (int i = 0; i < 2; i++) {
      int e = i * 256 + tid;  // 8-elem group: row e>>2, col (e&3)*8
      gll16(A + (size_t)(bm + (e >> 2)) * K + (k0 + (e & 3) * 8), &As[buf][e * 8]);
    }
#pragma unroll
    for (int i = 0; i < 2; i++) {
      int e = i * 256 + tid;
      gll16(B + (size_t)(bn + (e >> 2)) * K + (k0 + (e & 3) * 8), &Bs[buf][e * 8]);
    }
  };

  stage(0, 0);
  __syncthreads();
  const int nt = K / BK;
  for (int t = 0; t < nt; ++t) {
    int cur = t & 1;
    if (t + 1 < nt) stage(cur ^ 1, (t + 1) * BK);
    bf16x8 af[4], bfv[4];
#pragma unroll
    for (int m = 0; m < 4; m++)
      af[m] = *reinterpret_cast<const bf16x8*>(&As[cur][(wm + m * 16 + fr) * BK + fg * 8]);
#pragma unroll
    for (int n = 0; n < 4; n++)
      bfv[n] = *reinterpret_cast<const bf16x8*>(&Bs[cur][(wn + n * 16 + fr) * BK + fg * 8]);
#pragma unroll
    for (int m = 0; m < 4; m++)
#pragma unroll
      for (int n = 0; n < 4; n++)
        acc[m][n] = __builtin_amdgcn_mfma_f32_16x16x32_bf16(af[m], bfv[n], acc[m][n], 0, 0, 0);
    __syncthreads();
  }

#pragma unroll
  for (int m = 0; m < 4; m++)
#pragma unroll
    for (int n = 0; n < 4; n++)
#pragma unroll
      for (int j = 0; j < 4; j++) {
        size_t row = bm + wm + m * 16 + fg * 4 + j;
        size_t col = bn + wn + n * 16 + fr;
        if constexpr (OUT_BF16)
          reinterpret_cast<u16*>(Cv)[row * N + col] = f2bf(acc[m][n][j]);
        else
          reinterpret_cast<float*>(Cv)[row * N + col] = acc[m][n][j];
      }
}

// ---------------- fused RMSNorm + RoPE; one wave per (token, head-slot) ----
// Q rows are additionally scaled by 1/sqrt(128)*log2(e) so attention's
// softmax is a bare exp2.
__global__ __launch_bounds__(256) void rmsrope_kernel(
    const u16* __restrict__ qkv, const float* __restrict__ cosb,
    const float* __restrict__ sinb, const float* __restrict__ qw,
    const float* __restrict__ kw, u16* __restrict__ Q, u16* __restrict__ K) {
  int gw   = blockIdx.x * 4 + (threadIdx.x >> 6);
  int lane = threadIdx.x & 63;
  int tok  = gw / 20;
  int slot = gw - tok * 20;
  if (tok >= TOK) return;
  int b = tok >> 11, s = tok & (S_ - 1);
  const u16* src = qkv + (size_t)tok * OQKV + slot * HD_;
  float x0 = bf2f(src[lane]);
  float x1 = bf2f(src[lane + 64]);
  float ss = x0 * x0 + x1 * x1;
#pragma unroll
  for (int m = 1; m < 64; m <<= 1) ss += __shfl_xor(ss, m, 64);
  float r = rsqrtf(ss * (1.0f / 128.0f) + 1e-6f);
  const float* w = (slot < 16) ? qw : kw;
  x0 *= r * w[lane];
  x1 *= r * w[lane + 64];
  float c  = cosb[(size_t)tok * 64 + lane];
  float sn = sinb[(size_t)tok * 64 + lane];
  float partner = __shfl_xor(x0, 32, 64);
  float rot = (lane < 32) ? -partner : partner;
  x0 = x0 * c + rot * sn;
  const float QSC = 0.12751743f;  // (1/sqrt(128)) * log2(e)
  u16* dst;
  if (slot < 16) {
    x0 *= QSC; x1 *= QSC;
    dst = Q + (((size_t)b * NH_ + slot) * S_ + s) * HD_;
  } else {
    dst = K + (((size_t)b * NKV_ + (slot - 16)) * S_ + s) * HD_;
  }
  dst[lane]      = f2bf(x0);
  dst[lane + 64] = f2bf(x1);
}

// ---------------- flash attention v9: v7 staging + XCD-grouped blocks -----
// (round-12 verified: 104us, FETCH 12.4MB)
__global__ __launch_bounds__(512, 2) void attn_kernel(
    const u16* __restrict__ Q, const u16* __restrict__ K,
    const u16* __restrict__ QKVb, u16* __restrict__ O) {
  __shared__ __align__(16) u16 Ks[2][64 * 128];
  __shared__ __align__(16) u16 Vt[2][128 * 64];
  __shared__ float rs_lds[8][32];
  const int tid  = threadIdx.x;
  const int lane = tid & 63, wid = tid >> 6;
  const int q32 = lane & 31, hi = lane >> 5;
  const int i_   = blockIdx.x;
  const int xcd  = i_ & 7, s_ = i_ >> 3;
  const int b = xcd >> 2, kvh = xcd & 3;
  const int h = kvh * 4 + (s_ & 3);
  const int qt = s_ >> 2;                         // 0..7

  const u16* Qrow  = Q + ((size_t)(b * NH_ + h) * S_ + qt * 256 + wid * 32 + q32) * HD_;
  const u16* Kbase = K + (size_t)(b * NKV_ + kvh) * S_ * HD_;
  const u16* Vbase = QKVb + (size_t)b * S_ * OQKV + (size_t)(NH_ + NKV_) * HD_ + (size_t)kvh * HD_;

  bf16x8 qf[8];
#pragma unroll
  for (int m = 0; m < 8; m++)
    qf[m] = *reinterpret_cast<const bf16x8*>(Qrow + m * 16 + hi * 8);

  f32x16 acc[4];
#pragma unroll
  for (int n = 0; n < 4; n++)
#pragma unroll
    for (int r = 0; r < 16; r++) acc[n][r] = 0.f;

  float rs = 0.f;

  auto stageK = [&](int buf, int kt) {
#pragma unroll
    for (int i = 0; i < 2; i++) {
      int e = i * 512 + tid;
      int krow = e >> 4, ci = e & 15;
      int cs = ci ^ (krow & 15);
      gll16(Kbase + ((size_t)kt * 64 + krow) * HD_ + cs * 8, &Ks[buf][e * 8]);
    }
  };
  u16x8 vreg[4];
  auto loadV = [&](int kt) {
    if (tid < 256) {
      int kvb = tid >> 4, db = tid & 15;
#pragma unroll
      for (int i = 0; i < 4; i++)
        vreg[i] = *reinterpret_cast<const u16x8*>(
            Vbase + ((size_t)kt * 64 + kvb * 4 + i) * OQKV + db * 8);
    }
  };
  auto writeV = [&](int buf) {
    if (tid < 256) {
      int kvb = tid >> 4, db = tid & 15;
#pragma unroll
      for (int j = 0; j < 8; j++) {
        int d = db * 8 + j;
        int sw = (d ^ (d >> 3)) & 7;
        int off = d * 128 + ((((kvb >> 1) ^ sw)) << 4) + ((kvb & 1) << 3);
        short4v wv = {(short)vreg[0][j], (short)vreg[1][j],
                      (short)vreg[2][j], (short)vreg[3][j]};
        *reinterpret_cast<short4v*>(reinterpret_cast<char*>(Vt[buf]) + off) = wv;
      }
    }
  };

  stageK(0, 0);
  loadV(0);
  writeV(0);
  __syncthreads();

  const int NT = S_ / 64;  // 32
  for (int kt = 0; kt < NT; ++kt) {
    const int cur = kt & 1;
    if (kt + 1 < NT) { stageK(cur ^ 1, kt + 1); loadV(kt + 1); }

    const u16* kbp = &Ks[cur][(size_t)q32 * 128];
    const int swz = lane & 15;
    unsigned int pa[4][4];
#pragma unroll
    for (int kb = 0; kb < 2; kb++) {
      f32x16 s;
#pragma unroll
      for (int r = 0; r < 16; r++) s[r] = 0.f;
      __builtin_amdgcn_s_setprio(1);
#pragma unroll
      for (int m = 0; m < 8; m++) {
        bf16x8 kf = *reinterpret_cast<const bf16x8*>(
            kbp + kb * 32 * 128 + ((((m * 2 + hi) ^ swz)) << 3));
        s = __builtin_amdgcn_mfma_f32_32x32x16_bf16(kf, qf[m], s, 0, 0, 0);
      }
      __builtin_amdgcn_s_setprio(0);
      float p[16];
#pragma unroll
      for (int r = 0; r < 16; r++) {
        p[r] = exp2f(s[r]);
        rs += p[r];
      }
      unsigned int w[8];
#pragma unroll
      for (int m2 = 0; m2 < 8; m2++) {
        unsigned int wv;
        asm("v_cvt_pk_bf16_f32 %0, %1, %2" : "=v"(wv) : "v"(p[2 * m2]), "v"(p[2 * m2 + 1]));
        w[m2] = wv;
      }
#pragma unroll
      for (int tp = 0; tp < 2; tp++) {
        unsigned int a0 = w[4 * tp + 0], b0 = w[4 * tp + 2];
        unsigned int a1 = w[4 * tp + 1], b1 = w[4 * tp + 3];
        asm("v_permlane32_swap_b32 %0, %1" : "+v"(a0), "+v"(b0));
        asm("v_permlane32_swap_b32 %0, %1" : "+v"(a1), "+v"(b1));
        pa[kb * 2 + tp][0] = a0;
        pa[kb * 2 + tp][1] = a1;
        pa[kb * 2 + tp][2] = b0;
        pa[kb * 2 + tp][3] = b1;
      }
    }

#pragma unroll
    for (int t = 0; t < 4; t++) {
      union { u32x4 u; bf16x8 h; } pf;
      pf.u = (u32x4){pa[t][0], pa[t][1], pa[t][2], pa[t][3]};
      __builtin_amdgcn_s_setprio(1);
#pragma unroll
      for (int n = 0; n < 4; n++) {
        int d = n * 32 + q32;
        int sw = (d ^ (d >> 3)) & 7;
        bf16x8 vf = *reinterpret_cast<const bf16x8*>(
            reinterpret_cast<const char*>(Vt[cur]) + d * 128 + (((t * 2 + hi) ^ sw) << 4));
        acc[n] = __builtin_amdgcn_mfma_f32_32x32x16_bf16(pf.h, vf, acc[n], 0, 0, 0);
      }
      __builtin_amdgcn_s_setprio(0);
    }

    if (kt + 1 < NT) writeV(cur ^ 1);
    __syncthreads();
  }

  float rtot = rs + __shfl_xor(rs, 32, 64);
  if (lane < 32) rs_lds[wid][q32] = rtot;
  __syncthreads();
  float rinv[16];
#pragma unroll
  for (int r = 0; r < 16; r++)
    rinv[r] = 1.0f / rs_lds[wid][(r & 3) + 8 * (r >> 2) + 4 * hi];

  const int qrow0 = qt * 256 + wid * 32;
  u16* ob = O + ((size_t)b * S_ + qrow0) * HID_ + h * HD_ + q32;
#pragma unroll
  for (int n = 0; n < 4; n++)
#pragma unroll
    for (int r = 0; r < 16; r++) {
      int qr = (r & 3) + 8 * (r >> 2) + 4 * hi;
      ob[(size_t)qr * HID_ + n * 32] = f2bf(acc[n][r] * rinv[r]);
    }
}

// ---------------------------------------------------------------------------
extern "C" void kernel_launch(void* const* d_in, const int* in_sizes, int n_in,
                              void* d_out, int out_size, void* d_ws, size_t ws_size,
                              hipStream_t stream) {
  (void)in_sizes; (void)n_in; (void)out_size; (void)ws_size;
  const float* hs   = (const float*)d_in[0];
  const float* cosb = (const float*)d_in[1];
  const float* sinb = (const float*)d_in[2];
  const float* wqkv = (const float*)d_in[3];
  const float* qw   = (const float*)d_in[4];
  const float* kw   = (const float*)d_in[5];
  const float* wd   = (const float*)d_in[6];
  float* out = (float*)d_out;
  char* ws = (char*)d_ws;
  constexpr size_t MB = 1048576;
  u16* Xb    = (u16*)(ws + 0 * MB);    // 16 MB  X bf16        [4096][2048]
  u16* Wqkvb = (u16*)(ws + 16 * MB);   // 12 MB  w_qkv bf16    [3072][2048]
  u16* Wdb   = (u16*)(ws + 28 * MB);   //  8 MB  w_dense bf16  [2048][2048]
  u16* QKVb  = (u16*)(ws + 36 * MB);   // 24 MB  qkv bf16      [4096][3072]
  u16* Qb    = (u16*)(ws + 60 * MB);   // 16 MB  Q             [B][NH][S][HD]
  u16* Kb    = (u16*)(ws + 76 * MB);   //  4 MB  K             [B][NKV][S][HD]
  u16* Ob    = (u16*)(ws + 80 * MB);   // 16 MB  attn out      [B][S][NH*HD]

  cvt3_kernel<<<2048, 256, 0, stream>>>(hs, Xb, TOK * HID_ / 8,
                                        wqkv, Wqkvb, OQKV * HID_ / 8,
                                        wd, Wdb, HID_ * HID_ / 8);

  // 1-D grids: gx*gy blocks, XCD-chunked decode inside the kernel
  gemm_bt_kernel<true><<<(TOK / 128) * (OQKV / 128), 256, 0, stream>>>(
      Xb, Wqkvb, QKVb, TOK, OQKV, HID_);

  rmsrope_kernel<<<TOK * 20 / 4, 256, 0, stream>>>(QKVb, cosb, sinb, qw, kw, Qb, Kb);

  attn_kernel<<<256, 512, 0, stream>>>(Qb, Kb, QKVb, Ob);

  gemm_bt_kernel<false><<<(TOK / 128) * (HID_ / 128), 256, 0, stream>>>(
      Ob, Wdb, out, TOK, HID_, HID_);
}

// Round 16
// 225.017 us; speedup vs baseline: 1.1327x; 1.0087x over previous
//
#include <hip/hip_runtime.h>
#include <cstdint>
#include <cstddef>

typedef unsigned short u16;
typedef __attribute__((ext_vector_type(8))) short bf16x8;   // 8 bf16 (4 VGPR) MFMA frag
typedef __attribute__((ext_vector_type(8))) u16   u16x8;
typedef __attribute__((ext_vector_type(4))) short short4v;
typedef __attribute__((ext_vector_type(4))) float f32x4;
typedef __attribute__((ext_vector_type(16))) float f32x16;
typedef __attribute__((ext_vector_type(4))) unsigned int u32x4;

#define DEVI static __device__ __forceinline__

constexpr int B_   = 2;
constexpr int S_   = 2048;
constexpr int HID_ = 2048;
constexpr int NH_  = 16;
constexpr int NKV_ = 4;
constexpr int HD_  = 128;
constexpr int TOK  = B_ * S_;              // 4096
constexpr int OQKV = (NH_ + 2*NKV_) * HD_; // 3072

DEVI u16 f2bf(float f) {                  // RNE f32->bf16 (finite inputs)
  uint32_t u = __builtin_bit_cast(uint32_t, f);
  return (u16)((u + 0x7fffu + ((u >> 16) & 1u)) >> 16);
}
DEVI float bf2f(u16 h) { return __builtin_bit_cast(float, (uint32_t)h << 16); }

DEVI void gll16(const void* g, void* l) { // 16B global -> LDS direct
  __builtin_amdgcn_global_load_lds(
      (const __attribute__((address_space(1))) uint32_t*)g,
      (__attribute__((address_space(3))) uint32_t*)l, 16, 0, 0);
}

// ---------------- f32 -> bf16 convert, 3 buffers in one launch ------------
__global__ __launch_bounds__(256) void cvt3_kernel(
    const float* __restrict__ i0, u16* __restrict__ o0, int n0,
    const float* __restrict__ i1, u16* __restrict__ o1, int n1,
    const float* __restrict__ i2, u16* __restrict__ o2, int n2) {
  int idx = blockIdx.x * 256 + threadIdx.x;
  int stride = gridDim.x * 256;
#pragma unroll 1
  for (int pass = 0; pass < 3; ++pass) {
    const float* in = pass == 0 ? i0 : pass == 1 ? i1 : i2;
    u16* out       = pass == 0 ? o0 : pass == 1 ? o1 : o2;
    int n8         = pass == 0 ? n0 : pass == 1 ? n1 : n2;
    for (int i = idx; i < n8; i += stride) {
      const float4* p = reinterpret_cast<const float4*>(in) + (size_t)i * 2;
      float4 a = p[0], b = p[1];
      u16x8 v;
      v[0] = f2bf(a.x); v[1] = f2bf(a.y); v[2] = f2bf(a.z); v[3] = f2bf(a.w);
      v[4] = f2bf(b.x); v[5] = f2bf(b.y); v[6] = f2bf(b.z); v[7] = f2bf(b.w);
      reinterpret_cast<u16x8*>(out)[i] = v;
    }
  }
}

// ---------------- C[m,n] = sum_k A[m,k] * B[n,k]  (both row-major, bf16) ---
// Round-12-verified 128x128 structure (BK=32, 4 waves, global_load_lds,
// double-buffer; ~900 TF via 4 blocks/CU TLP). 2-D grid (the XCD-chunk
// swizzle variant measured -4us: operands are L3-resident, so the L2
// locality it buys is already free and the remap perturbs A-panel reuse).
template <bool OUT_BF16>
__global__ __launch_bounds__(256) void gemm_bt_kernel(
    const u16* __restrict__ A, const u16* __restrict__ B, void* __restrict__ Cv,
    int M, int N, int K) {
  constexpr int BM = 128, BN = 128, BK = 32;
  __shared__ __align__(16) u16 As[2][BM * BK];
  __shared__ __align__(16) u16 Bs[2][BN * BK];
  const int tid  = threadIdx.x;
  const int lane = tid & 63;
  const int wid  = tid >> 6;
  const int bm = blockIdx.x * BM;
  const int bn = blockIdx.y * BN;
  const int wm = (wid >> 1) * 64;
  const int wn = (wid & 1) * 64;
  const int fr = lane & 15, fg = lane >> 4;

  const f32x4 fzero = {0.f, 0.f, 0.f, 0.f};
  f32x4 acc[4][4];
#pragma unroll
  for (int m = 0; m < 4; m++)
#pragma unroll
    for (int n = 0; n < 4; n++) acc[m][n] = fzero;

  auto stage = [&](int buf, int k0) {
#pragma unroll
    for (int i = 0; i < 2; i++) {
      int e = i * 256 + tid;  // 8-elem group: row e>>2, col (e&3)*8
      gll16(A + (size_t)(bm + (e >> 2)) * K + (k0 + (e & 3) * 8), &As[buf][e * 8]);
    }
#pragma unroll
    for (int i = 0; i < 2; i++) {
      int e = i * 256 + tid;
      gll16(B + (size_t)(bn + (e >> 2)) * K + (k0 + (e & 3) * 8), &Bs[buf][e * 8]);
    }
  };

  stage(0, 0);
  __syncthreads();
  const int nt = K / BK;
  for (int t = 0; t < nt; ++t) {
    int cur = t & 1;
    if (t + 1 < nt) stage(cur ^ 1, (t + 1) * BK);
    bf16x8 af[4], bfv[4];
#pragma unroll
    for (int m = 0; m < 4; m++)
      af[m] = *reinterpret_cast<const bf16x8*>(&As[cur][(wm + m * 16 + fr) * BK + fg * 8]);
#pragma unroll
    for (int n = 0; n < 4; n++)
      bfv[n] = *reinterpret_cast<const bf16x8*>(&Bs[cur][(wn + n * 16 + fr) * BK + fg * 8]);
#pragma unroll
    for (int m = 0; m < 4; m++)
#pragma unroll
      for (int n = 0; n < 4; n++)
        acc[m][n] = __builtin_amdgcn_mfma_f32_16x16x32_bf16(af[m], bfv[n], acc[m][n], 0, 0, 0);
    __syncthreads();
  }

#pragma unroll
  for (int m = 0; m < 4; m++)
#pragma unroll
    for (int n = 0; n < 4; n++)
#pragma unroll
      for (int j = 0; j < 4; j++) {
        size_t row = bm + wm + m * 16 + fg * 4 + j;
        size_t col = bn + wn + n * 16 + fr;
        if constexpr (OUT_BF16)
          reinterpret_cast<u16*>(Cv)[row * N + col] = f2bf(acc[m][n][j]);
        else
          reinterpret_cast<float*>(Cv)[row * N + col] = acc[m][n][j];
      }
}

// ---------------- fused RMSNorm + RoPE; one wave per (token, head-slot) ----
// Q rows are additionally scaled by 1/sqrt(128)*log2(e) so attention's
// softmax is a bare exp2.
__global__ __launch_bounds__(256) void rmsrope_kernel(
    const u16* __restrict__ qkv, const float* __restrict__ cosb,
    const float* __restrict__ sinb, const float* __restrict__ qw,
    const float* __restrict__ kw, u16* __restrict__ Q, u16* __restrict__ K) {
  int gw   = blockIdx.x * 4 + (threadIdx.x >> 6);
  int lane = threadIdx.x & 63;
  int tok  = gw / 20;
  int slot = gw - tok * 20;
  if (tok >= TOK) return;
  int b = tok >> 11, s = tok & (S_ - 1);
  const u16* src = qkv + (size_t)tok * OQKV + slot * HD_;
  float x0 = bf2f(src[lane]);
  float x1 = bf2f(src[lane + 64]);
  float ss = x0 * x0 + x1 * x1;
#pragma unroll
  for (int m = 1; m < 64; m <<= 1) ss += __shfl_xor(ss, m, 64);
  float r = rsqrtf(ss * (1.0f / 128.0f) + 1e-6f);
  const float* w = (slot < 16) ? qw : kw;
  x0 *= r * w[lane];
  x1 *= r * w[lane + 64];
  float c  = cosb[(size_t)tok * 64 + lane];
  float sn = sinb[(size_t)tok * 64 + lane];
  float partner = __shfl_xor(x0, 32, 64);
  float rot = (lane < 32) ? -partner : partner;
  x0 = x0 * c + rot * sn;
  const float QSC = 0.12751743f;  // (1/sqrt(128)) * log2(e)
  u16* dst;
  if (slot < 16) {
    x0 *= QSC; x1 *= QSC;
    dst = Q + (((size_t)b * NH_ + slot) * S_ + s) * HD_;
  } else {
    dst = K + (((size_t)b * NKV_ + (slot - 16)) * S_ + s) * HD_;
  }
  dst[lane]      = f2bf(x0);
  dst[lane + 64] = f2bf(x1);
}

// ---------------- flash attention v9: v7 staging + XCD-grouped blocks -----
// (round-12 verified: 104us, FETCH 12.4MB)
__global__ __launch_bounds__(512, 2) void attn_kernel(
    const u16* __restrict__ Q, const u16* __restrict__ K,
    const u16* __restrict__ QKVb, u16* __restrict__ O) {
  __shared__ __align__(16) u16 Ks[2][64 * 128];
  __shared__ __align__(16) u16 Vt[2][128 * 64];
  __shared__ float rs_lds[8][32];
  const int tid  = threadIdx.x;
  const int lane = tid & 63, wid = tid >> 6;
  const int q32 = lane & 31, hi = lane >> 5;
  const int i_   = blockIdx.x;
  const int xcd  = i_ & 7, s_ = i_ >> 3;
  const int b = xcd >> 2, kvh = xcd & 3;
  const int h = kvh * 4 + (s_ & 3);
  const int qt = s_ >> 2;                         // 0..7

  const u16* Qrow  = Q + ((size_t)(b * NH_ + h) * S_ + qt * 256 + wid * 32 + q32) * HD_;
  const u16* Kbase = K + (size_t)(b * NKV_ + kvh) * S_ * HD_;
  const u16* Vbase = QKVb + (size_t)b * S_ * OQKV + (size_t)(NH_ + NKV_) * HD_ + (size_t)kvh * HD_;

  bf16x8 qf[8];
#pragma unroll
  for (int m = 0; m < 8; m++)
    qf[m] = *reinterpret_cast<const bf16x8*>(Qrow + m * 16 + hi * 8);

  f32x16 acc[4];
#pragma unroll
  for (int n = 0; n < 4; n++)
#pragma unroll
    for (int r = 0; r < 16; r++) acc[n][r] = 0.f;

  float rs = 0.f;

  auto stageK = [&](int buf, int kt) {
#pragma unroll
    for (int i = 0; i < 2; i++) {
      int e = i * 512 + tid;
      int krow = e >> 4, ci = e & 15;
      int cs = ci ^ (krow & 15);
      gll16(Kbase + ((size_t)kt * 64 + krow) * HD_ + cs * 8, &Ks[buf][e * 8]);
    }
  };
  u16x8 vreg[4];
  auto loadV = [&](int kt) {
    if (tid < 256) {
      int kvb = tid >> 4, db = tid & 15;
#pragma unroll
      for (int i = 0; i < 4; i++)
        vreg[i] = *reinterpret_cast<const u16x8*>(
            Vbase + ((size_t)kt * 64 + kvb * 4 + i) * OQKV + db * 8);
    }
  };
  auto writeV = [&](int buf) {
    if (tid < 256) {
      int kvb = tid >> 4, db = tid & 15;
#pragma unroll
      for (int j = 0; j < 8; j++) {
        int d = db * 8 + j;
        int sw = (d ^ (d >> 3)) & 7;
        int off = d * 128 + ((((kvb >> 1) ^ sw)) << 4) + ((kvb & 1) << 3);
        short4v wv = {(short)vreg[0][j], (short)vreg[1][j],
                      (short)vreg[2][j], (short)vreg[3][j]};
        *reinterpret_cast<short4v*>(reinterpret_cast<char*>(Vt[buf]) + off) = wv;
      }
    }
  };

  stageK(0, 0);
  loadV(0);
  writeV(0);
  __syncthreads();

  const int NT = S_ / 64;  // 32
  for (int kt = 0; kt < NT; ++kt) {
    const int cur = kt & 1;
    if (kt + 1 < NT) { stageK(cur ^ 1, kt + 1); loadV(kt + 1); }

    const u16* kbp = &Ks[cur][(size_t)q32 * 128];
    const int swz = lane & 15;
    unsigned int pa[4][4];
#pragma unroll
    for (int kb = 0; kb < 2; kb++) {
      f32x16 s;
#pragma unroll
      for (int r = 0; r < 16; r++) s[r] = 0.f;
      __builtin_amdgcn_s_setprio(1);
#pragma unroll
      for (int m = 0; m < 8; m++) {
        bf16x8 kf = *reinterpret_cast<const bf16x8*>(
            kbp + kb * 32 * 128 + ((((m * 2 + hi) ^ swz)) << 3));
        s = __builtin_amdgcn_mfma_f32_32x32x16_bf16(kf, qf[m], s, 0, 0, 0);
      }
      __builtin_amdgcn_s_setprio(0);
      float p[16];
#pragma unroll
      for (int r = 0; r < 16; r++) {
        p[r] = exp2f(s[r]);
        rs += p[r];
      }
      unsigned int w[8];
#pragma unroll
      for (int m2 = 0; m2 < 8; m2++) {
        unsigned int wv;
        asm("v_cvt_pk_bf16_f32 %0, %1, %2" : "=v"(wv) : "v"(p[2 * m2]), "v"(p[2 * m2 + 1]));
        w[m2] = wv;
      }
#pragma unroll
      for (int tp = 0; tp < 2; tp++) {
        unsigned int a0 = w[4 * tp + 0], b0 = w[4 * tp + 2];
        unsigned int a1 = w[4 * tp + 1], b1 = w[4 * tp + 3];
        asm("v_permlane32_swap_b32 %0, %1" : "+v"(a0), "+v"(b0));
        asm("v_permlane32_swap_b32 %0, %1" : "+v"(a1), "+v"(b1));
        pa[kb * 2 + tp][0] = a0;
        pa[kb * 2 + tp][1] = a1;
        pa[kb * 2 + tp][2] = b0;
        pa[kb * 2 + tp][3] = b1;
      }
    }

#pragma unroll
    for (int t = 0; t < 4; t++) {
      union { u32x4 u; bf16x8 h; } pf;
      pf.u = (u32x4){pa[t][0], pa[t][1], pa[t][2], pa[t][3]};
      __builtin_amdgcn_s_setprio(1);
#pragma unroll
      for (int n = 0; n < 4; n++) {
        int d = n * 32 + q32;
        int sw = (d ^ (d >> 3)) & 7;
        bf16x8 vf = *reinterpret_cast<const bf16x8*>(
            reinterpret_cast<const char*>(Vt[cur]) + d * 128 + (((t * 2 + hi) ^ sw) << 4));
        acc[n] = __builtin_amdgcn_mfma_f32_32x32x16_bf16(pf.h, vf, acc[n], 0, 0, 0);
      }
      __builtin_amdgcn_s_setprio(0);
    }

    if (kt + 1 < NT) writeV(cur ^ 1);
    __syncthreads();
  }

  float rtot = rs + __shfl_xor(rs, 32, 64);
  if (lane < 32) rs_lds[wid][q32] = rtot;
  __syncthreads();
  float rinv[16];
#pragma unroll
  for (int r = 0; r < 16; r++)
    rinv[r] = 1.0f / rs_lds[wid][(r & 3) + 8 * (r >> 2) + 4 * hi];

  const int qrow0 = qt * 256 + wid * 32;
  u16* ob = O + ((size_t)b * S_ + qrow0) * HID_ + h * HD_ + q32;
#pragma unroll
  for (int n = 0; n < 4; n++)
#pragma unroll
    for (int r = 0; r < 16; r++) {
      int qr = (r & 3) + 8 * (r >> 2) + 4 * hi;
      ob[(size_t)qr * HID_ + n * 32] = f2bf(acc[n][r] * rinv[r]);
    }
}

// ---------------------------------------------------------------------------
extern "C" void kernel_launch(void* const* d_in, const int* in_sizes, int n_in,
                              void* d_out, int out_size, void* d_ws, size_t ws_size,
                              hipStream_t stream) {
  (void)in_sizes; (void)n_in; (void)out_size; (void)ws_size;
  const float* hs   = (const float*)d_in[0];
  const float* cosb = (const float*)d_in[1];
  const float* sinb = (const float*)d_in[2];
  const float* wqkv = (const float*)d_in[3];
  const float* qw   = (const float*)d_in[4];
  const float* kw   = (const float*)d_in[5];
  const float* wd   = (const float*)d_in[6];
  float* out = (float*)d_out;
  char* ws = (char*)d_ws;
  constexpr size_t MB = 1048576;
  u16* Xb    = (u16*)(ws + 0 * MB);    // 16 MB  X bf16        [4096][2048]
  u16* Wqkvb = (u16*)(ws + 16 * MB);   // 12 MB  w_qkv bf16    [3072][2048]
  u16* Wdb   = (u16*)(ws + 28 * MB);   //  8 MB  w_dense bf16  [2048][2048]
  u16* QKVb  = (u16*)(ws + 36 * MB);   // 24 MB  qkv bf16      [4096][3072]
  u16* Qb    = (u16*)(ws + 60 * MB);   // 16 MB  Q             [B][NH][S][HD]
  u16* Kb    = (u16*)(ws + 76 * MB);   //  4 MB  K             [B][NKV][S][HD]
  u16* Ob    = (u16*)(ws + 80 * MB);   // 16 MB  attn out      [B][S][NH*HD]

  cvt3_kernel<<<2048, 256, 0, stream>>>(hs, Xb, TOK * HID_ / 8,
                                        wqkv, Wqkvb, OQKV * HID_ / 8,
                                        wd, Wdb, HID_ * HID_ / 8);

  gemm_bt_kernel<true><<<dim3(TOK / 128, OQKV / 128), 256, 0, stream>>>(
      Xb, Wqkvb, QKVb, TOK, OQKV, HID_);

  rmsrope_kernel<<<TOK * 20 / 4, 256, 0, stream>>>(QKVb, cosb, sinb, qw, kw, Qb, Kb);

  attn_kernel<<<256, 512, 0, stream>>>(Qb, Kb, QKVb, Ob);

  gemm_bt_kernel<false><<<dim3(TOK / 128, HID_ / 128), 256, 0, stream>>>(
      Ob, Wdb, out, TOK, HID_, HID_);
}